// Round 3
// baseline (957.532 us; speedup 1.0000x reference)
//
#include <hip/hip_runtime.h>

// DynamicSparseScaledDotProductAttention on MI355X (gfx950)
// q,k,v: [32, 2048, 64] fp32; gate_w: [1,64]; gate_b: [1]
// outputs (tuple): out [32,2048,64] fp32, attn [32,2048,2048] fp32
//
// v4: latency attack.
//  - v3 was MLP-limited: 377MB refetch (attn write stream evicted K/V from L2)
//    + only 16 waves/CU. Fixes:
//  - NT stores for ATT/OUT (bypass/no-allocate L2) -> K/V stay L2-resident.
//  - XCD-chunked block swizzle in BOTH kernels: XCD x owns bh [4x,4x+4)
//    (2MB K/V bf16 working set < 4MB L2/XCD; prep writes land in-XCD).
//  - 32-query blocks (grid 2048) + osum aliased onto Pbuf (per-wave pool):
//    LDS 36.9KB -> 19KB, 8 blocks/CU; occupancy VGPR-limited ~20-24 waves/CU.
//  - #pragma unroll 2 on key loops: two iterations' loads in flight, Pbuf
//    parity becomes compile-time.
// Compute structure (verified v3): gate-split, key-split flash across 4 waves,
// skewed pass-2 pipeline (compute P[kt] while consuming P[kt-1]).
//
// MFMA mfma_f32_16x16x32_bf16 layouts (HW-verified per guide):
//   A-frag: lane holds A[m=lane&15][k=(lane>>4)*8 + j], j=0..7
//   B-frag: lane holds B[k=(lane>>4)*8+j][n=lane&15]
//   C/D   : lane holds D[row=(lane>>4)*4 + r][col=lane&15], r=0..3

typedef short bf16x8 __attribute__((ext_vector_type(8)));
typedef float f32x4  __attribute__((ext_vector_type(4)));

#define LSEQ 2048
#define DDIM 64
#define PB_STRIDE 36   // Pbuf row stride (f32); 2-way max bank aliasing (free)
#define OS_STRIDE 68   // osum row stride (f32); 2-way max bank aliasing (free)
#define POOLF 1168     // per-wave pool floats: >= 2*16*36=1152 (Pbuf), >= 16*68=1088 (osum)

__device__ __forceinline__ unsigned short f2bf(float x) {
    // round-to-nearest-even fp32 -> bf16
    unsigned int u = __float_as_uint(x);
    u += 0x7FFFu + ((u >> 16) & 1u);
    return (unsigned short)(u >> 16);
}

__device__ __forceinline__ unsigned int pk2f(float a, float b) {
    return (unsigned int)f2bf(a) | ((unsigned int)f2bf(b) << 16);
}

__device__ __forceinline__ unsigned int pk2u(unsigned short a, unsigned short b) {
    return (unsigned int)a | ((unsigned int)b << 16);
}

__device__ __forceinline__ float pick5(int jj, float e0, float e1, float e2,
                                       float e3, float e4) {
    float r = 0.f;
    r = (jj == 0) ? e0 : r;
    r = (jj == 1) ? e1 : r;
    r = (jj == 2) ? e2 : r;
    r = (jj == 3) ? e3 : r;
    r = (jj == 4) ? e4 : r;
    return r;
}

// ---------------- prep: K -> bf16 [bh][key][d]; V -> bf16 transposed [bh][d][key]
__global__ __launch_bounds__(256)
void dsa_prep(const float* __restrict__ K, const float* __restrict__ V,
              unsigned short* __restrict__ Kb, unsigned short* __restrict__ Vt)
{
    // XCD-chunked swizzle (nwg=1024, 8 XCDs): XCD x handles bh [4x, 4x+4)
    const int bx  = blockIdx.x;
    const int w   = ((bx & 7) << 7) + (bx >> 3);
    const int bh  = w >> 5;
    const int k0  = (w & 31) << 6;            // 64-key chunk
    const int tid = threadIdx.x;
    __shared__ unsigned short tileT[64][73];  // [d][key] (+pad)

    const int key = tid >> 2;                 // 0..63
    const int d0  = (tid & 3) << 4;           // 0,16,32,48
    const float* srcK = K + ((size_t)bh * LSEQ + k0 + key) * DDIM + d0;
    const float* srcV = V + ((size_t)bh * LSEQ + k0 + key) * DDIM + d0;
    {   // K: straight convert, 16 elems/thread, 2x16B stores
        uint4 w0, w1;
        w0.x = pk2f(srcK[0],  srcK[1]);  w0.y = pk2f(srcK[2],  srcK[3]);
        w0.z = pk2f(srcK[4],  srcK[5]);  w0.w = pk2f(srcK[6],  srcK[7]);
        w1.x = pk2f(srcK[8],  srcK[9]);  w1.y = pk2f(srcK[10], srcK[11]);
        w1.z = pk2f(srcK[12], srcK[13]); w1.w = pk2f(srcK[14], srcK[15]);
        unsigned short* dst = Kb + ((size_t)bh * LSEQ + k0 + key) * DDIM + d0;
        *(uint4*)(dst)     = w0;
        *(uint4*)(dst + 8) = w1;
    }
    #pragma unroll
    for (int j = 0; j < 16; ++j) tileT[d0 + j][key] = f2bf(srcV[j]);
    __syncthreads();
    {   // V: write transposed rows coalesced
        const int d   = tid >> 2;
        const int kk0 = (tid & 3) << 4;
        uint4 w0, w1;
        w0.x = pk2u(tileT[d][kk0 + 0],  tileT[d][kk0 + 1]);
        w0.y = pk2u(tileT[d][kk0 + 2],  tileT[d][kk0 + 3]);
        w0.z = pk2u(tileT[d][kk0 + 4],  tileT[d][kk0 + 5]);
        w0.w = pk2u(tileT[d][kk0 + 6],  tileT[d][kk0 + 7]);
        w1.x = pk2u(tileT[d][kk0 + 8],  tileT[d][kk0 + 9]);
        w1.y = pk2u(tileT[d][kk0 + 10], tileT[d][kk0 + 11]);
        w1.z = pk2u(tileT[d][kk0 + 12], tileT[d][kk0 + 13]);
        w1.w = pk2u(tileT[d][kk0 + 14], tileT[d][kk0 + 15]);
        unsigned short* dst = Vt + (size_t)bh * DDIM * LSEQ + (size_t)d * LSEQ + k0 + kk0;
        *(uint4*)(dst)     = w0;
        *(uint4*)(dst + 8) = w1;
    }
}

// ---------------- main: 32 queries per block, 2048 blocks
__global__ __launch_bounds__(256)
void dsa_main(const float* __restrict__ Q,
              const unsigned short* __restrict__ Kb,   // bf16 [bh][key][d]
              const unsigned short* __restrict__ Vt,   // bf16 [bh][d][key]
              const float* __restrict__ K32,
              const float* __restrict__ V32,
              const float* __restrict__ GW,
              const float* __restrict__ GB,
              float* __restrict__ OUT,
              float* __restrict__ ATT)
{
    // Per-wave pool: Pbuf (double-buffered P tile) during pass 2, then aliased
    // as osum (partial O, 16 rows x 64, stride 68). Per-wave alias is safe:
    // osum is written only after that wave's last Pbuf read (in-order LDS).
    __shared__ float Pool[4][POOLF];
    __shared__ float dsum[4][16];   // per-wave partial denominators
    __shared__ int   sidx[32];      // full rows first, then window rows
    __shared__ int   gShared;

    // XCD-chunked swizzle (nwg=2048, 8 XCDs): XCD x handles bh [4x, 4x+4)
    const int bx   = blockIdx.x;
    const int w    = ((bx & 7) << 8) + (bx >> 3);
    const int bh   = w >> 6;
    const int q0   = (w & 63) << 5;   // 32-query tile
    const int tid  = threadIdx.x;
    const int wave = tid >> 6;
    const int lane = tid & 63;
    const int m16  = lane & 15;
    const int quad = lane >> 4;

    const float* qb = Q + ((size_t)bh * LSEQ + q0) * DDIM;

    // ---- gate (exact fp32: sigmoid(x)>0.5 <=> x>0) + ballot sort, wave 0 ----
    if (wave == 0) {
        const int row = lane & 31;
        const float* qr = qb + row * DDIM;
        float a = 0.f;
        #pragma unroll 8
        for (int d = 0; d < DDIM; ++d) a += qr[d] * GW[d];
        a += GB[0];
        const bool gt = (lane < 32) && (a > 0.f);
        const unsigned long long b = __ballot(gt);
        const int below = __popcll(b & ((1ull << lane) - 1ull));
        const int gg    = __popcll(b);
        if (lane < 32) {
            const int pos = gt ? below : (gg + (lane - below));
            sidx[pos] = lane;
        }
        if (lane == 0) gShared = gg;
    }
    __syncthreads();
    const int g = gShared;
    const int T = (g + 15) >> 4;   // full 16-row tiles (0..2)

    const unsigned short* kbb = Kb + (size_t)bh * LSEQ * DDIM;
    const unsigned short* vtb = Vt + (size_t)bh * DDIM * LSEQ;
    const int kbase = wave << 9;   // this wave's 512-key slice

    // =================== full tiles: all 4 waves cooperate (key-split) ============
    for (int t = 0; t < T; ++t) {
        const int  myIdx = (t << 4) + m16;
        const bool valid = myIdx < g;
        const int  srow  = sidx[valid ? myIdx : (g - 1)];

        // per-lane Q A-frags for this tile
        bf16x8 qfrag[2];
        {
            const float* qr = qb + srow * DDIM + (quad << 3);
            #pragma unroll
            for (int db = 0; db < 2; ++db) {
                const float* p = qr + db * 32;
                bf16x8 f;
                #pragma unroll
                for (int j = 0; j < 8; ++j) f[j] = (short)f2bf(p[j]);
                qfrag[db] = f;
            }
        }

        const unsigned short* kp0 = kbb + (size_t)(kbase + m16) * DDIM + (quad << 3);

        // ---- pass 1: partial denominators over my 512 keys ----
        float lsum[4] = {0.f, 0.f, 0.f, 0.f};
        #pragma unroll 2
        for (int kt = 0; kt < 16; ++kt) {
            const unsigned short* kp = kp0 + (size_t)(kt * 32) * DDIM;
            bf16x8 k0 = *(const bf16x8*)(kp);
            bf16x8 k1 = *(const bf16x8*)(kp + 32);
            bf16x8 k2 = *(const bf16x8*)(kp + 16 * DDIM);
            bf16x8 k3 = *(const bf16x8*)(kp + 16 * DDIM + 32);
            f32x4 a0 = {0.f, 0.f, 0.f, 0.f}, a1 = {0.f, 0.f, 0.f, 0.f};
            a0 = __builtin_amdgcn_mfma_f32_16x16x32_bf16(qfrag[0], k0, a0, 0, 0, 0);
            a0 = __builtin_amdgcn_mfma_f32_16x16x32_bf16(qfrag[1], k1, a0, 0, 0, 0);
            a1 = __builtin_amdgcn_mfma_f32_16x16x32_bf16(qfrag[0], k2, a1, 0, 0, 0);
            a1 = __builtin_amdgcn_mfma_f32_16x16x32_bf16(qfrag[1], k3, a1, 0, 0, 0);
            #pragma unroll
            for (int r = 0; r < 4; ++r)
                lsum[r] += __expf(a0[r] * 0.125f) + __expf(a1[r] * 0.125f);
        }
        #pragma unroll
        for (int r = 0; r < 4; ++r) {
            float x = lsum[r];
            x += __shfl_xor(x, 1); x += __shfl_xor(x, 2);
            x += __shfl_xor(x, 4); x += __shfl_xor(x, 8);
            if (m16 == 0) dsum[wave][(quad << 2) + r] = x;
        }
        __syncthreads();   // A: denominators complete

        float inv[4];
        #pragma unroll
        for (int r = 0; r < 4; ++r) {
            const int rr = (quad << 2) + r;
            inv[r] = 1.0f / (dsum[0][rr] + dsum[1][rr] + dsum[2][rr] + dsum[3][rr]);
        }

        // ---- pass 2 (skewed): compute P[kt], consume P[kt-1] ----
        f32x4 oacc0 = {0.f,0.f,0.f,0.f}, oacc1 = {0.f,0.f,0.f,0.f};
        f32x4 oacc2 = {0.f,0.f,0.f,0.f}, oacc3 = {0.f,0.f,0.f,0.f};
        float* ap0 = ATT + ((size_t)(bh * LSEQ + q0 + srow)) * LSEQ + kbase + (quad << 3);
        const unsigned short* vp0 = vtb + (size_t)m16 * LSEQ + kbase + (quad << 3);

        #define COMPUTE(KT_) {                                                        \
            const unsigned short* kp = kp0 + (size_t)((KT_) * 32) * DDIM;             \
            bf16x8 k0 = *(const bf16x8*)(kp);                                         \
            bf16x8 k1 = *(const bf16x8*)(kp + 32);                                    \
            bf16x8 k2 = *(const bf16x8*)(kp + 16 * DDIM);                             \
            bf16x8 k3 = *(const bf16x8*)(kp + 16 * DDIM + 32);                        \
            f32x4 a0 = {0.f,0.f,0.f,0.f}, a1 = {0.f,0.f,0.f,0.f};                     \
            a0 = __builtin_amdgcn_mfma_f32_16x16x32_bf16(qfrag[0], k0, a0, 0, 0, 0);  \
            a0 = __builtin_amdgcn_mfma_f32_16x16x32_bf16(qfrag[1], k1, a0, 0, 0, 0);  \
            a1 = __builtin_amdgcn_mfma_f32_16x16x32_bf16(qfrag[0], k2, a1, 0, 0, 0);  \
            a1 = __builtin_amdgcn_mfma_f32_16x16x32_bf16(qfrag[1], k3, a1, 0, 0, 0);  \
            float* pw = &Pool[wave][((KT_) & 1) * 576];                               \
            _Pragma("unroll")                                                         \
            for (int r = 0; r < 4; ++r) {                                             \
                const int prow = (quad << 2) + r;                                     \
                pw[prow * PB_STRIDE + m16]      = __expf(a0[r] * 0.125f) * inv[r];    \
                pw[prow * PB_STRIDE + 16 + m16] = __expf(a1[r] * 0.125f) * inv[r];    \
            }                                                                         \
        }

        #define CONSUME(KT_) {                                                        \
            const float* prd = &Pool[wave][((KT_) & 1) * 576] + m16 * PB_STRIDE + (quad << 3); \
            f32x4 p0 = *(const f32x4*)(prd);                                          \
            f32x4 p1 = *(const f32x4*)(prd + 4);                                      \
            const unsigned short* vp = vp0 + (KT_) * 32;                              \
            bf16x8 v0 = *(const bf16x8*)(vp);                                         \
            bf16x8 v1 = *(const bf16x8*)(vp + 16 * LSEQ);                             \
            bf16x8 v2 = *(const bf16x8*)(vp + 32 * LSEQ);                             \
            bf16x8 v3 = *(const bf16x8*)(vp + 48 * LSEQ);                             \
            if (valid) {                                                              \
                float* ap = ap0 + (KT_) * 32;                                         \
                __builtin_nontemporal_store(p0, (f32x4*)(ap));                        \
                __builtin_nontemporal_store(p1, (f32x4*)(ap + 4));                    \
            }                                                                         \
            bf16x8 pf;                                                                \
            _Pragma("unroll")                                                         \
            for (int j = 0; j < 4; ++j) {                                             \
                pf[j]     = (short)f2bf(p0[j]);                                       \
                pf[4 + j] = (short)f2bf(p1[j]);                                       \
            }                                                                         \
            oacc0 = __builtin_amdgcn_mfma_f32_16x16x32_bf16(pf, v0, oacc0, 0, 0, 0);  \
            oacc1 = __builtin_amdgcn_mfma_f32_16x16x32_bf16(pf, v1, oacc1, 0, 0, 0);  \
            oacc2 = __builtin_amdgcn_mfma_f32_16x16x32_bf16(pf, v2, oacc2, 0, 0, 0);  \
            oacc3 = __builtin_amdgcn_mfma_f32_16x16x32_bf16(pf, v3, oacc3, 0, 0, 0);  \
        }

        COMPUTE(0)
        #pragma unroll 2
        for (int kt = 1; kt < 16; ++kt) {
            CONSUME(kt - 1)
            COMPUTE(kt)
        }
        CONSUME(15)

        #undef COMPUTE
        #undef CONSUME

        // partial O -> Pool (aliases Pbuf; all of this wave's Pbuf reads are done)
        #pragma unroll
        for (int r = 0; r < 4; ++r) {
            const int prow = (quad << 2) + r;
            float* ow = &Pool[wave][prow * OS_STRIDE];
            ow[m16]      = oacc0[r];
            ow[16 + m16] = oacc1[r];
            ow[32 + m16] = oacc2[r];
            ow[48 + m16] = oacc3[r];
        }
        __syncthreads();   // B: partials complete

        // cross-wave O reduce + coalesced OUT store
        #pragma unroll
        for (int rep = 0; rep < 4; ++rep) {
            const int idx = rep * 256 + tid;      // 0..1023
            const int row = idx >> 6;             // 0..15
            const int col = idx & 63;
            const int gi  = (t << 4) + row;
            if (gi < g) {
                const float s = Pool[0][row * OS_STRIDE + col]
                              + Pool[1][row * OS_STRIDE + col]
                              + Pool[2][row * OS_STRIDE + col]
                              + Pool[3][row * OS_STRIDE + col];
                __builtin_nontemporal_store(
                    s, &OUT[((size_t)(bh * LSEQ + q0 + sidx[gi])) * DDIM + col]);
            }
        }
        __syncthreads();   // C: protect Pool/dsum reuse next tile
    }

    // =================== window rows (gate off): exact fp32, 5-key softmax =========
    const int nw = 32 - g;
    for (int ii = wave; ii < nw; ii += 4) {
        const int row = sidx[g + ii];
        const int i   = q0 + row;                       // global query index
        const float qd = qb[row * DDIM + lane];         // d = lane

        float e[5];
        float denom = 0.f;
        #pragma unroll
        for (int jj = 0; jj < 5; ++jj) {
            const int  j  = i - 2 + jj;
            const bool ok = (j >= 0) && (j < LSEQ);
            const int  jc = ok ? j : 0;
            float tt = qd * K32[((size_t)bh * LSEQ + jc) * DDIM + lane];
            tt += __shfl_xor(tt, 1);  tt += __shfl_xor(tt, 2);
            tt += __shfl_xor(tt, 4);  tt += __shfl_xor(tt, 8);
            tt += __shfl_xor(tt, 16); tt += __shfl_xor(tt, 32);
            const float ee = ok ? __expf(tt * 0.125f) : 0.f;
            e[jj] = ee;
            denom += ee;
        }
        const float invd = 1.f / denom;
        #pragma unroll
        for (int jj = 0; jj < 5; ++jj) e[jj] *= invd;

        // out row: o[d] = sum_j p_j * V[j][d]  (lane = d, coalesced)
        float o = 0.f;
        #pragma unroll
        for (int jj = 0; jj < 5; ++jj) {
            const int  j  = i - 2 + jj;
            const int  jc = (j >= 0 && j < LSEQ) ? j : 0;
            o += e[jj] * V32[((size_t)bh * LSEQ + jc) * DDIM + lane];
        }
        __builtin_nontemporal_store(o, &OUT[((size_t)(bh * LSEQ + i)) * DDIM + lane]);

        // attn row: zeros with the <=5 window values merged in-register
        float* ar = ATT + ((size_t)(bh * LSEQ + i)) * LSEQ;
        const int jlo = i - 2;
        #pragma unroll
        for (int it = 0; it < 8; ++it) {
            const int c = (it << 8) + (lane << 2);
            f32x4 z = {0.f, 0.f, 0.f, 0.f};
            if (c + 3 >= jlo && c <= jlo + 4) {
                #pragma unroll
                for (int t4 = 0; t4 < 4; ++t4)
                    z[t4] = pick5(c + t4 - jlo, e[0], e[1], e[2], e[3], e[4]);
            }
            __builtin_nontemporal_store(z, (f32x4*)(ar + c));
        }
    }
}

extern "C" void kernel_launch(void* const* d_in, const int* in_sizes, int n_in,
                              void* d_out, int out_size, void* d_ws, size_t ws_size,
                              hipStream_t stream) {
    const float* q  = (const float*)d_in[0];
    const float* k  = (const float*)d_in[1];
    const float* v  = (const float*)d_in[2];
    const float* gw = (const float*)d_in[3];
    const float* gb = (const float*)d_in[4];

    float* out  = (float*)d_out;                      // [32,2048,64]
    float* attn = out + (size_t)32 * 2048 * 64;       // [32,2048,2048]

    // workspace: Kb bf16 [32][2048][64] (8MB) + Vt bf16 [32][64][2048] (8MB)
    unsigned short* Kb = (unsigned short*)d_ws;
    unsigned short* Vt = Kb + (size_t)32 * 2048 * 64;

    dim3 block(256);
    dsa_prep<<<dim3(1024), block, 0, stream>>>(k, v, Kb, Vt);
    dsa_main<<<dim3(2048), block, 0, stream>>>(q, Kb, Vt, k, v, gw, gb, out, attn);
}

// Round 4
// 823.692 us; speedup vs baseline: 1.1625x; 1.1625x over previous
//
#include <hip/hip_runtime.h>

// DynamicSparseScaledDotProductAttention on MI355X (gfx950)
// q,k,v: [32, 2048, 64] fp32; gate_w: [1,64]; gate_b: [1]
// outputs (tuple): out [32,2048,64] fp32, attn [32,2048,2048] fp32
//
// v5: v4's memory wins without its register loss.
//  - v4 post-mortem: FETCH 377->116MB (NT + XCD swizzle: good) but VGPR 80->256
//    from '#pragma unroll 2' (occupancy 10.4%) and WRITE 542->786MB (NT attn
//    stores only fill 32B of each 64B sector per instruction -> RMW amp).
//  - Fix 1: no unroll pragmas -> VGPR back to ~100, 4-6 waves/SIMD.
//  - Fix 2: second LDS readback of the P tile with a store-friendly mapping
//    (row=lane>>2, col=(lane&3)*8): 4 adjacent lanes cover a row's 128B
//    contiguously -> every NT store writes full 64B sectors (no amplification).
//    The MFMA-layout readback still feeds PV.
//  - V loads issued at top of CONSUME so latency hides under LDS reads + store.
// Structure (verified v3/v4): gate-split, key-split flash across 4 waves,
// skewed pass-2 (compute P[kt] while consuming P[kt-1]), per-wave Pool with
// osum alias, XCD-chunked swizzle, 32-query blocks.
//
// MFMA mfma_f32_16x16x32_bf16 layouts (HW-verified per guide):
//   A-frag: lane holds A[m=lane&15][k=(lane>>4)*8 + j], j=0..7
//   B-frag: lane holds B[k=(lane>>4)*8+j][n=lane&15]
//   C/D   : lane holds D[row=(lane>>4)*4 + r][col=lane&15], r=0..3

typedef short bf16x8 __attribute__((ext_vector_type(8)));
typedef float f32x4  __attribute__((ext_vector_type(4)));

#define LSEQ 2048
#define DDIM 64
#define PB_STRIDE 36   // Pbuf row stride (f32); 2-way max bank aliasing (free)
#define OS_STRIDE 68   // osum row stride (f32); 2-way max bank aliasing (free)
#define POOLF 1168     // per-wave pool floats: >= 2*16*36=1152 (Pbuf), >= 16*68=1088 (osum)

__device__ __forceinline__ unsigned short f2bf(float x) {
    // round-to-nearest-even fp32 -> bf16
    unsigned int u = __float_as_uint(x);
    u += 0x7FFFu + ((u >> 16) & 1u);
    return (unsigned short)(u >> 16);
}

__device__ __forceinline__ unsigned int pk2f(float a, float b) {
    return (unsigned int)f2bf(a) | ((unsigned int)f2bf(b) << 16);
}

__device__ __forceinline__ unsigned int pk2u(unsigned short a, unsigned short b) {
    return (unsigned int)a | ((unsigned int)b << 16);
}

__device__ __forceinline__ float pick5(int jj, float e0, float e1, float e2,
                                       float e3, float e4) {
    float r = 0.f;
    r = (jj == 0) ? e0 : r;
    r = (jj == 1) ? e1 : r;
    r = (jj == 2) ? e2 : r;
    r = (jj == 3) ? e3 : r;
    r = (jj == 4) ? e4 : r;
    return r;
}

// ---------------- prep: K -> bf16 [bh][key][d]; V -> bf16 transposed [bh][d][key]
__global__ __launch_bounds__(256)
void dsa_prep(const float* __restrict__ K, const float* __restrict__ V,
              unsigned short* __restrict__ Kb, unsigned short* __restrict__ Vt)
{
    // XCD-chunked swizzle (nwg=1024, 8 XCDs): XCD x handles bh [4x, 4x+4)
    const int bx  = blockIdx.x;
    const int w   = ((bx & 7) << 7) + (bx >> 3);
    const int bh  = w >> 5;
    const int k0  = (w & 31) << 6;            // 64-key chunk
    const int tid = threadIdx.x;
    __shared__ unsigned short tileT[64][73];  // [d][key] (+pad)

    const int key = tid >> 2;                 // 0..63
    const int d0  = (tid & 3) << 4;           // 0,16,32,48
    const float* srcK = K + ((size_t)bh * LSEQ + k0 + key) * DDIM + d0;
    const float* srcV = V + ((size_t)bh * LSEQ + k0 + key) * DDIM + d0;
    {   // K: straight convert, 16 elems/thread, 2x16B stores
        uint4 w0, w1;
        w0.x = pk2f(srcK[0],  srcK[1]);  w0.y = pk2f(srcK[2],  srcK[3]);
        w0.z = pk2f(srcK[4],  srcK[5]);  w0.w = pk2f(srcK[6],  srcK[7]);
        w1.x = pk2f(srcK[8],  srcK[9]);  w1.y = pk2f(srcK[10], srcK[11]);
        w1.z = pk2f(srcK[12], srcK[13]); w1.w = pk2f(srcK[14], srcK[15]);
        unsigned short* dst = Kb + ((size_t)bh * LSEQ + k0 + key) * DDIM + d0;
        *(uint4*)(dst)     = w0;
        *(uint4*)(dst + 8) = w1;
    }
    #pragma unroll
    for (int j = 0; j < 16; ++j) tileT[d0 + j][key] = f2bf(srcV[j]);
    __syncthreads();
    {   // V: write transposed rows coalesced
        const int d   = tid >> 2;
        const int kk0 = (tid & 3) << 4;
        uint4 w0, w1;
        w0.x = pk2u(tileT[d][kk0 + 0],  tileT[d][kk0 + 1]);
        w0.y = pk2u(tileT[d][kk0 + 2],  tileT[d][kk0 + 3]);
        w0.z = pk2u(tileT[d][kk0 + 4],  tileT[d][kk0 + 5]);
        w0.w = pk2u(tileT[d][kk0 + 6],  tileT[d][kk0 + 7]);
        w1.x = pk2u(tileT[d][kk0 + 8],  tileT[d][kk0 + 9]);
        w1.y = pk2u(tileT[d][kk0 + 10], tileT[d][kk0 + 11]);
        w1.z = pk2u(tileT[d][kk0 + 12], tileT[d][kk0 + 13]);
        w1.w = pk2u(tileT[d][kk0 + 14], tileT[d][kk0 + 15]);
        unsigned short* dst = Vt + (size_t)bh * DDIM * LSEQ + (size_t)d * LSEQ + k0 + kk0;
        *(uint4*)(dst)     = w0;
        *(uint4*)(dst + 8) = w1;
    }
}

// ---------------- main: 32 queries per block, 2048 blocks
__global__ __launch_bounds__(256)
void dsa_main(const float* __restrict__ Q,
              const unsigned short* __restrict__ Kb,   // bf16 [bh][key][d]
              const unsigned short* __restrict__ Vt,   // bf16 [bh][d][key]
              const float* __restrict__ K32,
              const float* __restrict__ V32,
              const float* __restrict__ GW,
              const float* __restrict__ GB,
              float* __restrict__ OUT,
              float* __restrict__ ATT)
{
    // Per-wave pool: Pbuf (double-buffered P tile) during pass 2, then aliased
    // as osum (partial O, 16 rows x 64, stride 68). Per-wave alias is safe:
    // osum is written only after that wave's last Pbuf read (in-order LDS).
    __shared__ float Pool[4][POOLF];
    __shared__ float dsum[4][16];   // per-wave partial denominators
    __shared__ int   sidx[32];      // full rows first, then window rows
    __shared__ int   gShared;

    // XCD-chunked swizzle (nwg=2048, 8 XCDs): XCD x handles bh [4x, 4x+4)
    const int bx   = blockIdx.x;
    const int w    = ((bx & 7) << 8) + (bx >> 3);
    const int bh   = w >> 6;
    const int q0   = (w & 63) << 5;   // 32-query tile
    const int tid  = threadIdx.x;
    const int wave = tid >> 6;
    const int lane = tid & 63;
    const int m16  = lane & 15;
    const int quad = lane >> 4;

    const float* qb = Q + ((size_t)bh * LSEQ + q0) * DDIM;

    // ---- gate (exact fp32: sigmoid(x)>0.5 <=> x>0) + ballot sort, wave 0 ----
    if (wave == 0) {
        const int row = lane & 31;
        const float* qr = qb + row * DDIM;
        float a = 0.f;
        #pragma unroll 8
        for (int d = 0; d < DDIM; ++d) a += qr[d] * GW[d];
        a += GB[0];
        const bool gt = (lane < 32) && (a > 0.f);
        const unsigned long long b = __ballot(gt);
        const int below = __popcll(b & ((1ull << lane) - 1ull));
        const int gg    = __popcll(b);
        if (lane < 32) {
            const int pos = gt ? below : (gg + (lane - below));
            sidx[pos] = lane;
        }
        if (lane == 0) gShared = gg;
    }
    __syncthreads();
    const int g = gShared;
    const int T = (g + 15) >> 4;   // full 16-row tiles (0..2)

    const unsigned short* kbb = Kb + (size_t)bh * LSEQ * DDIM;
    const unsigned short* vtb = Vt + (size_t)bh * DDIM * LSEQ;
    const int kbase = wave << 9;   // this wave's 512-key slice

    // store-mapping lane coords (full-sector attn stores)
    const int srowLoc = lane >> 2;         // 0..15
    const int scol    = (lane & 3) << 3;   // 0,8,16,24

    // =================== full tiles: all 4 waves cooperate (key-split) ============
    for (int t = 0; t < T; ++t) {
        const int  myIdx = (t << 4) + m16;
        const bool valid = myIdx < g;
        const int  srow  = sidx[valid ? myIdx : (g - 1)];

        // store-mapping row for this tile
        const int  sIdx2  = (t << 4) + srowLoc;
        const bool valid2 = sIdx2 < g;
        const int  srow2  = sidx[valid2 ? sIdx2 : (g - 1)];
        float* ap2 = ATT + ((size_t)(bh * LSEQ + q0 + srow2)) * LSEQ + kbase + scol;

        // per-lane Q A-frags for this tile
        bf16x8 qfrag[2];
        {
            const float* qr = qb + srow * DDIM + (quad << 3);
            #pragma unroll
            for (int db = 0; db < 2; ++db) {
                const float* p = qr + db * 32;
                bf16x8 f;
                #pragma unroll
                for (int j = 0; j < 8; ++j) f[j] = (short)f2bf(p[j]);
                qfrag[db] = f;
            }
        }

        const unsigned short* kp0 = kbb + (size_t)(kbase + m16) * DDIM + (quad << 3);

        // ---- pass 1: partial denominators over my 512 keys ----
        float lsum[4] = {0.f, 0.f, 0.f, 0.f};
        for (int kt = 0; kt < 16; ++kt) {
            const unsigned short* kp = kp0 + (size_t)(kt * 32) * DDIM;
            bf16x8 k0 = *(const bf16x8*)(kp);
            bf16x8 k1 = *(const bf16x8*)(kp + 32);
            bf16x8 k2 = *(const bf16x8*)(kp + 16 * DDIM);
            bf16x8 k3 = *(const bf16x8*)(kp + 16 * DDIM + 32);
            f32x4 a0 = {0.f, 0.f, 0.f, 0.f}, a1 = {0.f, 0.f, 0.f, 0.f};
            a0 = __builtin_amdgcn_mfma_f32_16x16x32_bf16(qfrag[0], k0, a0, 0, 0, 0);
            a0 = __builtin_amdgcn_mfma_f32_16x16x32_bf16(qfrag[1], k1, a0, 0, 0, 0);
            a1 = __builtin_amdgcn_mfma_f32_16x16x32_bf16(qfrag[0], k2, a1, 0, 0, 0);
            a1 = __builtin_amdgcn_mfma_f32_16x16x32_bf16(qfrag[1], k3, a1, 0, 0, 0);
            #pragma unroll
            for (int r = 0; r < 4; ++r)
                lsum[r] += __expf(a0[r] * 0.125f) + __expf(a1[r] * 0.125f);
        }
        #pragma unroll
        for (int r = 0; r < 4; ++r) {
            float x = lsum[r];
            x += __shfl_xor(x, 1); x += __shfl_xor(x, 2);
            x += __shfl_xor(x, 4); x += __shfl_xor(x, 8);
            if (m16 == 0) dsum[wave][(quad << 2) + r] = x;
        }
        __syncthreads();   // A: denominators complete

        float inv[4];
        #pragma unroll
        for (int r = 0; r < 4; ++r) {
            const int rr = (quad << 2) + r;
            inv[r] = 1.0f / (dsum[0][rr] + dsum[1][rr] + dsum[2][rr] + dsum[3][rr]);
        }

        // ---- pass 2 (skewed): compute P[kt], consume P[kt-1] ----
        f32x4 oacc0 = {0.f,0.f,0.f,0.f}, oacc1 = {0.f,0.f,0.f,0.f};
        f32x4 oacc2 = {0.f,0.f,0.f,0.f}, oacc3 = {0.f,0.f,0.f,0.f};
        const unsigned short* vp0 = vtb + (size_t)m16 * LSEQ + kbase + (quad << 3);

        #define COMPUTE(KT_) {                                                        \
            const unsigned short* kp = kp0 + (size_t)((KT_) * 32) * DDIM;             \
            bf16x8 k0 = *(const bf16x8*)(kp);                                         \
            bf16x8 k1 = *(const bf16x8*)(kp + 32);                                    \
            bf16x8 k2 = *(const bf16x8*)(kp + 16 * DDIM);                             \
            bf16x8 k3 = *(const bf16x8*)(kp + 16 * DDIM + 32);                        \
            f32x4 a0 = {0.f,0.f,0.f,0.f}, a1 = {0.f,0.f,0.f,0.f};                     \
            a0 = __builtin_amdgcn_mfma_f32_16x16x32_bf16(qfrag[0], k0, a0, 0, 0, 0);  \
            a0 = __builtin_amdgcn_mfma_f32_16x16x32_bf16(qfrag[1], k1, a0, 0, 0, 0);  \
            a1 = __builtin_amdgcn_mfma_f32_16x16x32_bf16(qfrag[0], k2, a1, 0, 0, 0);  \
            a1 = __builtin_amdgcn_mfma_f32_16x16x32_bf16(qfrag[1], k3, a1, 0, 0, 0);  \
            float* pw = &Pool[wave][((KT_) & 1) * 576];                               \
            _Pragma("unroll")                                                         \
            for (int r = 0; r < 4; ++r) {                                             \
                const int prow = (quad << 2) + r;                                     \
                pw[prow * PB_STRIDE + m16]      = __expf(a0[r] * 0.125f) * inv[r];    \
                pw[prow * PB_STRIDE + 16 + m16] = __expf(a1[r] * 0.125f) * inv[r];    \
            }                                                                         \
        }

        #define CONSUME(KT_) {                                                        \
            const unsigned short* vp = vp0 + (KT_) * 32;                              \
            bf16x8 v0 = *(const bf16x8*)(vp);                                         \
            bf16x8 v1 = *(const bf16x8*)(vp + 16 * LSEQ);                             \
            bf16x8 v2 = *(const bf16x8*)(vp + 32 * LSEQ);                             \
            bf16x8 v3 = *(const bf16x8*)(vp + 48 * LSEQ);                             \
            const float* pb = &Pool[wave][((KT_) & 1) * 576];                         \
            const float* prd = pb + m16 * PB_STRIDE + (quad << 3);                    \
            f32x4 p0 = *(const f32x4*)(prd);                                          \
            f32x4 p1 = *(const f32x4*)(prd + 4);                                      \
            const float* srd = pb + srowLoc * PB_STRIDE + scol;                       \
            f32x4 s0 = *(const f32x4*)(srd);                                          \
            f32x4 s1 = *(const f32x4*)(srd + 4);                                      \
            if (valid2) {                                                             \
                float* ap = ap2 + (KT_) * 32;                                         \
                __builtin_nontemporal_store(s0, (f32x4*)(ap));                        \
                __builtin_nontemporal_store(s1, (f32x4*)(ap + 4));                    \
            }                                                                         \
            bf16x8 pf;                                                                \
            _Pragma("unroll")                                                         \
            for (int j = 0; j < 4; ++j) {                                             \
                pf[j]     = (short)f2bf(p0[j]);                                       \
                pf[4 + j] = (short)f2bf(p1[j]);                                       \
            }                                                                         \
            oacc0 = __builtin_amdgcn_mfma_f32_16x16x32_bf16(pf, v0, oacc0, 0, 0, 0);  \
            oacc1 = __builtin_amdgcn_mfma_f32_16x16x32_bf16(pf, v1, oacc1, 0, 0, 0);  \
            oacc2 = __builtin_amdgcn_mfma_f32_16x16x32_bf16(pf, v2, oacc2, 0, 0, 0);  \
            oacc3 = __builtin_amdgcn_mfma_f32_16x16x32_bf16(pf, v3, oacc3, 0, 0, 0);  \
        }

        COMPUTE(0)
        for (int kt = 1; kt < 16; ++kt) {
            CONSUME(kt - 1)
            COMPUTE(kt)
        }
        CONSUME(15)

        #undef COMPUTE
        #undef CONSUME

        // partial O -> Pool (aliases Pbuf; all of this wave's Pbuf reads are done)
        #pragma unroll
        for (int r = 0; r < 4; ++r) {
            const int prow = (quad << 2) + r;
            float* ow = &Pool[wave][prow * OS_STRIDE];
            ow[m16]      = oacc0[r];
            ow[16 + m16] = oacc1[r];
            ow[32 + m16] = oacc2[r];
            ow[48 + m16] = oacc3[r];
        }
        __syncthreads();   // B: partials complete

        // cross-wave O reduce + coalesced OUT store
        #pragma unroll
        for (int rep = 0; rep < 4; ++rep) {
            const int idx = rep * 256 + tid;      // 0..1023
            const int row = idx >> 6;             // 0..15
            const int col = idx & 63;
            const int gi  = (t << 4) + row;
            if (gi < g) {
                const float s = Pool[0][row * OS_STRIDE + col]
                              + Pool[1][row * OS_STRIDE + col]
                              + Pool[2][row * OS_STRIDE + col]
                              + Pool[3][row * OS_STRIDE + col];
                __builtin_nontemporal_store(
                    s, &OUT[((size_t)(bh * LSEQ + q0 + sidx[gi])) * DDIM + col]);
            }
        }
        __syncthreads();   // C: protect Pool/dsum reuse next tile
    }

    // =================== window rows (gate off): exact fp32, 5-key softmax =========
    const int nw = 32 - g;
    for (int ii = wave; ii < nw; ii += 4) {
        const int row = sidx[g + ii];
        const int i   = q0 + row;                       // global query index
        const float qd = qb[row * DDIM + lane];         // d = lane

        float e[5];
        float denom = 0.f;
        #pragma unroll
        for (int jj = 0; jj < 5; ++jj) {
            const int  j  = i - 2 + jj;
            const bool ok = (j >= 0) && (j < LSEQ);
            const int  jc = ok ? j : 0;
            float tt = qd * K32[((size_t)bh * LSEQ + jc) * DDIM + lane];
            tt += __shfl_xor(tt, 1);  tt += __shfl_xor(tt, 2);
            tt += __shfl_xor(tt, 4);  tt += __shfl_xor(tt, 8);
            tt += __shfl_xor(tt, 16); tt += __shfl_xor(tt, 32);
            const float ee = ok ? __expf(tt * 0.125f) : 0.f;
            e[jj] = ee;
            denom += ee;
        }
        const float invd = 1.f / denom;
        #pragma unroll
        for (int jj = 0; jj < 5; ++jj) e[jj] *= invd;

        // out row: o[d] = sum_j p_j * V[j][d]  (lane = d, coalesced)
        float o = 0.f;
        #pragma unroll
        for (int jj = 0; jj < 5; ++jj) {
            const int  j  = i - 2 + jj;
            const int  jc = (j >= 0 && j < LSEQ) ? j : 0;
            o += e[jj] * V32[((size_t)bh * LSEQ + jc) * DDIM + lane];
        }
        __builtin_nontemporal_store(o, &OUT[((size_t)(bh * LSEQ + i)) * DDIM + lane]);

        // attn row: zeros with the <=5 window values merged in-register
        float* ar = ATT + ((size_t)(bh * LSEQ + i)) * LSEQ;
        const int jlo = i - 2;
        #pragma unroll
        for (int it = 0; it < 8; ++it) {
            const int c = (it << 8) + (lane << 2);
            f32x4 z = {0.f, 0.f, 0.f, 0.f};
            if (c + 3 >= jlo && c <= jlo + 4) {
                #pragma unroll
                for (int t4 = 0; t4 < 4; ++t4)
                    z[t4] = pick5(c + t4 - jlo, e[0], e[1], e[2], e[3], e[4]);
            }
            __builtin_nontemporal_store(z, (f32x4*)(ar + c));
        }
    }
}

extern "C" void kernel_launch(void* const* d_in, const int* in_sizes, int n_in,
                              void* d_out, int out_size, void* d_ws, size_t ws_size,
                              hipStream_t stream) {
    const float* q  = (const float*)d_in[0];
    const float* k  = (const float*)d_in[1];
    const float* v  = (const float*)d_in[2];
    const float* gw = (const float*)d_in[3];
    const float* gb = (const float*)d_in[4];

    float* out  = (float*)d_out;                      // [32,2048,64]
    float* attn = out + (size_t)32 * 2048 * 64;       // [32,2048,2048]

    // workspace: Kb bf16 [32][2048][64] (8MB) + Vt bf16 [32][64][2048] (8MB)
    unsigned short* Kb = (unsigned short*)d_ws;
    unsigned short* Vt = Kb + (size_t)32 * 2048 * 64;

    dim3 block(256);
    dsa_prep<<<dim3(1024), block, 0, stream>>>(k, v, Kb, Vt);
    dsa_main<<<dim3(2048), block, 0, stream>>>(q, Kb, Vt, k, v, gw, gb, out, attn);
}